// Round 11
// baseline (206.901 us; speedup 1.0000x reference)
//
#include <hip/hip_runtime.h>
#include <hip/hip_bf16.h>
#include <stdint.h>

// ---------------- problem constants ----------------
#define NB   32
#define NC   256
#define NOC  256
#define HWD  56
#define NPIX 3136      // 56*56 = 14 * 224 exactly
#define PW   58        // padded row width
#define PPIX 3364      // 58*58
#define KTOT 2304      // 9 * 256
#define MOD  512       // fc1 out channels
#define GAPD 16

// workspace layout (bytes)
#define XBT_BYTES ((size_t)NB * PPIX * NC * 2)            // 55,115,776
#define WA_BYTES  ((size_t)NB * NOC * KTOT * 2)           // 37,748,736

typedef __bf16 bf16x8 __attribute__((ext_vector_type(8)));
typedef float  f32x4  __attribute__((ext_vector_type(4)));
typedef unsigned short u16x8 __attribute__((ext_vector_type(8)));

__device__ __forceinline__ unsigned short f2bf(float f) {
    union { float f; unsigned int u; } v; v.f = f;
    unsigned int u = v.u;
    return (unsigned short)((u + 0x7FFFu + ((u >> 16) & 1u)) >> 16);
}

// ---------------- P1: per-batch conv weights, SE fused in; one block per oc ----------------
__global__ void wk_kernel(const float* __restrict__ gap,
                          const float* __restrict__ rw, const float* __restrict__ rb,
                          const float* __restrict__ f1w,
                          const float* __restrict__ f2w, const float* __restrict__ f2b,
                          unsigned short* __restrict__ wa) {
    __shared__ float sgap[NB * 257];    // stride 257: bank-spread
    __shared__ float srw[GAPD * 257];
    __shared__ float ssg[NB * GAPD];
    __shared__ float sa[2 * NB];
    __shared__ float sw[KTOT];
    __shared__ float sbv[KTOT];
    int oc = blockIdx.x, c = threadIdx.x;
    // stage gap (32x256 = 8192) and rw (16x256 = 4096), padded stride
    #pragma unroll
    for (int i = 0; i < 32; ++i) {
        int idx = i * 256 + c;                     // 0..8191
        sgap[(idx >> 8) * 257 + (idx & 255)] = gap[idx];
    }
    #pragma unroll
    for (int i = 0; i < 16; ++i) {
        int idx = i * 256 + c;                     // 0..4095
        srw[(idx >> 8) * 257 + (idx & 255)] = rw[idx];
    }
    // stage this oc's fc2 row
    const float4* wsrc = (const float4*)(f2w + (size_t)oc * KTOT);
    const float4* bsrc = (const float4*)(f2b + (size_t)oc * KTOT);
    #pragma unroll
    for (int i = 0; i < 3; ++i) {
        int idx = i * 256 + c;
        if (idx < 576) {
            ((float4*)sw)[idx] = wsrc[idx];
            ((float4*)sbv)[idx] = bsrc[idx];
        }
    }
    __syncthreads();
    // sg[b][tt] = rb[tt] + gap[b,:] . rw[tt,:]   (512 pairs, 2 per thread)
    #pragma unroll
    for (int e = 0; e < 2; ++e) {
        int pair = c * 2 + e;
        int b = pair >> 4, tt = pair & 15;
        float s = rb[tt];
        for (int k = 0; k < NC; ++k) s += sgap[b * 257 + k] * srw[tt * 257 + k];
        ssg[b * GAPD + tt] = s;
    }
    __syncthreads();
    // a(b, 2oc+e) for all 32 b x 2 e: threads c<64
    if (c < 64) {
        int b = c >> 1, e = c & 1;
        float s = 0.f;
        #pragma unroll
        for (int tt = 0; tt < GAPD; ++tt)
            s += ssg[b * GAPD + tt] * f1w[(2 * oc + e) * GAPD + tt];
        sa[c] = 1.0f / (1.0f + __expf(-s));
    }
    __syncthreads();
    float w9[9], b9[9];
    #pragma unroll
    for (int s = 0; s < 9; ++s) { w9[s] = sw[c * 9 + s]; b9[s] = sbv[c * 9 + s]; }
    for (int b = 0; b < NB; ++b) {
        float a0 = sa[2 * b], a1 = sa[2 * b + 1];
        unsigned short* dst = wa + (size_t)(b * NOC + oc) * KTOT;
        #pragma unroll
        for (int s = 0; s < 9; ++s) {
            float a = ((c * 9 + s) >= 1152) ? a1 : a0;
            dst[s * NC + c] = f2bf(a * w9[s] + b9[s]);
        }
    }
}

// ---------------- P2: zero xbt halo + zero gap ----------------
__global__ void halo_kernel(unsigned short* __restrict__ xbt, float* __restrict__ gap) {
    int b = blockIdx.x, t = threadIdx.x;
    gap[b * NC + t] = 0.f;
    unsigned short* xb = xbt + (size_t)b * PPIX * NC;
    u16x8 z = {};
    for (int i = t; i < 3712; i += 256) {
        int r = (i >= 1856) ? 1 : 0;
        int c = i - r * 1856;
        int pix = r * (57 * 58) + (c >> 5);
        *(u16x8*)(xb + (size_t)pix * NC + (c & 31) * 8) = z;
    }
    for (int i = t; i < 3584; i += 256) {
        int row = 1 + (i >> 6);
        int side = (i >> 5) & 1;
        int pix = row * PW + side * 57;
        *(u16x8*)(xb + (size_t)pix * NC + (i & 31) * 8) = z;
    }
}

// ---------------- P3: x -> bf16 NHWC with halo, shuffle-reduced GAP ----------------
#define TSTR 59
__global__ void xpose_kernel(const float* __restrict__ x, unsigned short* __restrict__ xbt,
                             float* __restrict__ gap) {
    __shared__ unsigned short tile[NC * TSTR];
    int py = blockIdx.x, b = blockIdx.y, t = threadIdx.x;
    int wv = t >> 6, l = t & 63;
    const float* xs = x + (size_t)b * NC * NPIX + py * HWD;
    int q = l & 15;
    int rb4 = l >> 4;
    #pragma unroll
    for (int it = 0; it < 16; ++it) {
        int c = wv * 64 + it * 4 + rb4;
        float4 v = {0.f, 0.f, 0.f, 0.f};
        if (q < 14) {
            v = *(const float4*)(xs + (size_t)c * NPIX + q * 4);
            unsigned short* tr = tile + c * TSTR + q * 4;
            tr[0] = f2bf(v.x); tr[1] = f2bf(v.y); tr[2] = f2bf(v.z); tr[3] = f2bf(v.w);
        }
        // fused GAP: reduce row-sum across the 16 q-lanes (bits 0-3 of lane id)
        float s4 = v.x + v.y + v.z + v.w;
        s4 += __shfl_xor(s4, 1);
        s4 += __shfl_xor(s4, 2);
        s4 += __shfl_xor(s4, 4);
        s4 += __shfl_xor(s4, 8);
        if (q == 0) atomicAdd(&gap[b * NC + c], s4 * (1.0f / NPIX));
    }
    __syncthreads();
    int cch = t & 31, pg = t >> 5;
    for (int i = 0; i < 7; ++i) {
        int px = pg * 7 + i;
        u16x8 v;
        #pragma unroll
        for (int j = 0; j < 8; ++j) v[j] = tile[(cch * 8 + j) * TSTR + px];
        *(u16x8*)(xbt + ((size_t)b * PPIX + (size_t)(1 + py) * PW + 1 + px) * NC + cch * 8) = v;
    }
}

// ---------------- main GEMM: 256oc x 224px tile, 8 waves (4M x 2N, wave 64x112) ----------------
// BK=64: 36 phases (half the sync events of R10). Slice = 64 KB laid out as FOUR
// R10-proven 16 KB half-panels: [A-k0][A-k1][B-k0][B-k1]; each half internally the
// verified 1KB-unit swizzle (0 conflicts). Ring-2 = 128 KB. Per phase: vmcnt(8) +
// barrier -> compute (k0 reads+MFMA, k1 reads+MFMA, no barrier between halves ->
// lgkm slip) -> barrier -> issue next-next slice into the just-read slot (WAR-safe).
#define SLICE 65536

#define PWAIT(N) do { asm volatile("s_waitcnt vmcnt(" #N ")" ::: "memory"); \
    __builtin_amdgcn_s_barrier(); __builtin_amdgcn_sched_barrier(0); } while (0)

__global__ __launch_bounds__(512, 2) void conv_gemm(
    const unsigned short* __restrict__ wa,   // [32][256][2304] bf16
    const unsigned short* __restrict__ xbt,  // [32][3364][256] bf16 (padded NHWC)
    float* __restrict__ out)                 // [32][256][3136]
{
    __shared__ __attribute__((aligned(16))) char lds[2 * SLICE];  // 128 KB

    // XCD swizzle: 448 blocks = 8 XCD * 56; 4 whole batches per XCD
    const int bid = blockIdx.x;
    const int wg  = (bid & 7) * 56 + (bid >> 3);
    const int b   = wg / 14, nt = wg % 14;

    const int t = threadIdx.x;
    const int w = t >> 6, l = t & 63;            // 8 waves
    const int wm = w >> 1, wn = w & 1;           // 4M x 2N, wave tile 64oc x 112px

    const unsigned short* waB = wa + (size_t)b * NOC * KTOT;
    const unsigned short* xbB = xbt + (size_t)b * PPIX * NC;

    // ---- staging sources (pre-swizzled, R10 mapping): chunk c = j*512 + t ----
    const unsigned short* srcA[2];
    const unsigned short* srcB[2];
    #pragma unroll
    for (int j = 0; j < 2; ++j) {
        int cix = j * 512 + t;
        int cc  = cix & 63;
        int row = (cix >> 6) * 16 + (cc >> 2);
        int qv  = (cc & 3) ^ ((cc >> 3) & 3);
        srcA[j] = waB + (size_t)row * KTOT + qv * 8;
        int pg = nt * 224 + row; if (pg > NPIX - 1) pg = NPIX - 1;  // pad units only
        int py = pg / 56, px = pg - py * 56;
        srcB[j] = xbB + (size_t)((py + 1) * PW + (px + 1)) * NC + qv * 8;
    }
    const int t16 = t * 16;

    // stage K-tile kt (64 wide) into slot: 8 gload_lds/thread
    auto issue = [&](int kt, int slot) {
        char* sb = lds + slot * SLICE;
        const int s9 = kt >> 2;
        const int dy = (s9 >= 6) ? 2 : ((s9 >= 3) ? 1 : 0);
        const int dx = s9 - dy * 3;
        const int bsh = ((dy - 1) * PW + (dx - 1)) * NC + (kt & 3) * 64;
        #pragma unroll
        for (int h = 0; h < 2; ++h) {         // k-half
            #pragma unroll
            for (int j = 0; j < 2; ++j)
                __builtin_amdgcn_global_load_lds(
                    (const __attribute__((address_space(1))) void*)(srcA[j] + kt * 64 + h * 32),
                    (__attribute__((address_space(3))) void*)(sb + h * 16384 + j * 8192 + t16),
                    16, 0, 0);
            #pragma unroll
            for (int j = 0; j < 2; ++j)
                __builtin_amdgcn_global_load_lds(
                    (const __attribute__((address_space(1))) void*)(srcB[j] + bsh + h * 32),
                    (__attribute__((address_space(3))) void*)(sb + 32768 + h * 16384 + j * 8192 + t16),
                    16, 0, 0);
        }
    };

    // ---- read-side lane constants (R10-proven, 0 conflicts) ----
    const int physq16 = (((l >> 4) ^ ((l >> 1) & 3)) << 4);
    const int arow = (l & 15) << 6;

    f32x4 acc[4][7] = {};

    auto compute = [&](int slot) {
        const char* sb = lds + slot * SLICE;
        #pragma unroll
        for (int h = 0; h < 2; ++h) {
            const char* ab = sb + h * 16384;
            bf16x8 af[4], bfr[7];
            #pragma unroll
            for (int m = 0; m < 4; ++m)
                af[m] = *(const bf16x8*)(ab + (wm * 4 + m) * 1024 + arow + physq16);
            #pragma unroll
            for (int j = 0; j < 7; ++j)
                bfr[j] = *(const bf16x8*)(ab + 32768 + (wn * 7 + j) * 1024 + arow + physq16);
            __builtin_amdgcn_s_setprio(1);
            #pragma unroll
            for (int m = 0; m < 4; ++m)
                #pragma unroll
                for (int j = 0; j < 7; ++j)
                    acc[m][j] = __builtin_amdgcn_mfma_f32_16x16x32_bf16(af[m], bfr[j], acc[m][j], 0, 0, 0);
            __builtin_amdgcn_s_setprio(0);
        }
    };

    issue(0, 0); issue(1, 1);

    #pragma unroll 2
    for (int p = 0; p < 35; ++p) {
        PWAIT(8);                                  // K-tile p resident (8 newest = p+1)
        compute(p & 1);
        __builtin_amdgcn_s_barrier();              // all reads of slot p&1 done
        __builtin_amdgcn_sched_barrier(0);
        if (p < 34) issue(p + 2, p & 1);           // WAR-safe: after barrier2
    }
    PWAIT(0);                                      // p = 35: drain
    compute(1);

    // epilogue: D lane map col = l&15 (pixel), row = (l>>4)*4 + r (oc)
    const int ocb = wm * 64 + ((l >> 4) << 2);
    const int pxb = nt * 224 + wn * 112 + (l & 15);
    #pragma unroll
    for (int i = 0; i < 4; ++i) {
        #pragma unroll
        for (int j = 0; j < 7; ++j) {
            float* o = out + ((size_t)(b * NOC + ocb + i * 16)) * NPIX + pxb + j * 16;
            o[0]        = acc[i][j][0];
            o[NPIX]     = acc[i][j][1];
            o[2 * NPIX] = acc[i][j][2];
            o[3 * NPIX] = acc[i][j][3];
        }
    }
}

extern "C" void kernel_launch(void* const* d_in, const int* in_sizes, int n_in,
                              void* d_out, int out_size, void* d_ws, size_t ws_size,
                              hipStream_t stream) {
    (void)in_sizes; (void)n_in; (void)out_size; (void)ws_size;
    const float* x   = (const float*)d_in[0];
    const float* rw  = (const float*)d_in[1];
    const float* rb  = (const float*)d_in[2];
    const float* f1w = (const float*)d_in[3];
    const float* f2w = (const float*)d_in[4];
    const float* f2b = (const float*)d_in[5];
    float* out = (float*)d_out;

    char* wsb = (char*)d_ws;
    unsigned short* xbt = (unsigned short*)wsb;
    unsigned short* wa  = (unsigned short*)(wsb + XBT_BYTES);
    float* gap = (float*)(wsb + XBT_BYTES + WA_BYTES);

    halo_kernel<<<dim3(32), 256, 0, stream>>>(xbt, gap);
    xpose_kernel<<<dim3(56, 32), 256, 0, stream>>>(x, xbt, gap);
    wk_kernel<<<dim3(256), 256, 0, stream>>>(gap, rw, rb, f1w, f2w, f2b, wa);
    conv_gemm<<<dim3(448), 512, 0, stream>>>(wa, xbt, out);
}

// Round 12
// 191.198 us; speedup vs baseline: 1.0821x; 1.0821x over previous
//
#include <hip/hip_runtime.h>
#include <hip/hip_bf16.h>
#include <stdint.h>

// ---------------- problem constants ----------------
#define NB   32
#define NC   256
#define NOC  256
#define HWD  56
#define NPIX 3136      // 56*56 = 14 * 224 exactly
#define PW   58        // padded row width
#define PPIX 3364      // 58*58
#define KTOT 2304      // 9 * 256
#define MOD  512       // fc1 out channels
#define GAPD 16

// workspace layout (bytes)
#define XBT_BYTES ((size_t)NB * PPIX * NC * 2)            // 55,115,776
#define WA_BYTES  ((size_t)NB * NOC * KTOT * 2)           // 37,748,736

typedef __bf16 bf16x8 __attribute__((ext_vector_type(8)));
typedef float  f32x4  __attribute__((ext_vector_type(4)));
typedef unsigned short u16x8 __attribute__((ext_vector_type(8)));

__device__ __forceinline__ unsigned short f2bf(float f) {
    union { float f; unsigned int u; } v; v.f = f;
    unsigned int u = v.u;
    return (unsigned short)((u + 0x7FFFu + ((u >> 16) & 1u)) >> 16);
}

// ---------------- P1: per-batch conv weights, SE fused; LDS-transpose wide stores ----------------
__global__ void wk_kernel(const float* __restrict__ gap,
                          const float* __restrict__ rw, const float* __restrict__ rb,
                          const float* __restrict__ f1w,
                          const float* __restrict__ f2w, const float* __restrict__ f2b,
                          unsigned short* __restrict__ wa) {
    __shared__ float sgap[NB * 257];    // stride 257: bank-spread
    __shared__ float srw[GAPD * 257];
    __shared__ float ssg[NB * GAPD];
    __shared__ float sa[2 * NB];
    __shared__ float sw[KTOT];
    __shared__ float sbv[KTOT];
    __shared__ unsigned short sx[9 * 264];   // per-b transpose buffer
    int oc = blockIdx.x, c = threadIdx.x;
    // stage gap (32x256 = 8192) and rw (16x256 = 4096), padded stride
    #pragma unroll
    for (int i = 0; i < 32; ++i) {
        int idx = i * 256 + c;
        sgap[(idx >> 8) * 257 + (idx & 255)] = gap[idx];
    }
    #pragma unroll
    for (int i = 0; i < 16; ++i) {
        int idx = i * 256 + c;
        srw[(idx >> 8) * 257 + (idx & 255)] = rw[idx];
    }
    // stage this oc's fc2 row
    const float4* wsrc = (const float4*)(f2w + (size_t)oc * KTOT);
    const float4* bsrc = (const float4*)(f2b + (size_t)oc * KTOT);
    #pragma unroll
    for (int i = 0; i < 3; ++i) {
        int idx = i * 256 + c;
        if (idx < 576) {
            ((float4*)sw)[idx] = wsrc[idx];
            ((float4*)sbv)[idx] = bsrc[idx];
        }
    }
    __syncthreads();
    // sg[b][tt] = rb[tt] + gap[b,:] . rw[tt,:]   (512 pairs, 2 per thread)
    #pragma unroll
    for (int e = 0; e < 2; ++e) {
        int pair = c * 2 + e;
        int b = pair >> 4, tt = pair & 15;
        float s = rb[tt];
        for (int k = 0; k < NC; ++k) s += sgap[b * 257 + k] * srw[tt * 257 + k];
        ssg[b * GAPD + tt] = s;
    }
    __syncthreads();
    // a(b, 2oc+e) for all 32 b x 2 e: threads c<64
    if (c < 64) {
        int b = c >> 1, e = c & 1;
        float s = 0.f;
        #pragma unroll
        for (int tt = 0; tt < GAPD; ++tt)
            s += ssg[b * GAPD + tt] * f1w[(2 * oc + e) * GAPD + tt];
        sa[c] = 1.0f / (1.0f + __expf(-s));
    }
    __syncthreads();
    // per-c weight/bias registers (lane stride 9 words -> conflict-free)
    float w9[9], b9[9];
    #pragma unroll
    for (int s = 0; s < 9; ++s) { w9[s] = sw[c * 9 + s]; b9[s] = sbv[c * 9 + s]; }
    // rem = c*9+s >= 1152  <=>  c >= 128 (uniform over s)
    const int hi = (c >= 128);
    // chunk-read constants: thread t -> chunk t (s=t>>5, cg=t&31); t<32 also chunk 256+t
    const int rd1 = (c >> 5) * 528 + (c & 31) * 16;      // byte offset into sx
    const int rd2 = 8 * 528 + c * 16;                    // s=8 row (t<32)
    for (int b = 0; b < NB; ++b) {
        float a = hi ? sa[2 * b + 1] : sa[2 * b];
        #pragma unroll
        for (int s = 0; s < 9; ++s)
            sx[s * 264 + c] = f2bf(a * w9[s] + b9[s]);
        __syncthreads();
        unsigned short* dst = wa + (size_t)(b * NOC + oc) * KTOT;
        {   // chunk t: elems s*256 + cg*8 .. +7
            u16x8 v = *(const u16x8*)((const char*)sx + rd1);
            *(u16x8*)(dst + (c >> 5) * 256 + (c & 31) * 8) = v;
        }
        if (c < 32) {   // chunk 256+t: s=8
            u16x8 v = *(const u16x8*)((const char*)sx + rd2);
            *(u16x8*)(dst + 8 * 256 + c * 8) = v;
        }
        __syncthreads();
    }
}

// ---------------- P2: x -> bf16 NHWC, halo fused, shuffle-reduced GAP ----------------
#define TSTR 59
__global__ void xpose_kernel(const float* __restrict__ x, unsigned short* __restrict__ xbt,
                             float* __restrict__ gap) {
    __shared__ unsigned short tile[NC * TSTR];
    int py = blockIdx.x, b = blockIdx.y, t = threadIdx.x;
    int wv = t >> 6, l = t & 63;
    const u16x8 z = {};
    unsigned short* xb = xbt + (size_t)b * PPIX * NC;
    // fused halo: side columns (px 0 and 57) of this block's padded row
    if (t < 64)
        *(u16x8*)(xb + ((size_t)(1 + py) * PW + ((t >= 32) ? 57 : 0)) * NC + (t & 31) * 8) = z;
    // top full padded row (pixels 0..57) by py==0; bottom (row 57) by py==55
    if (py == 0)
        for (int i = t; i < 1856; i += 256)
            *(u16x8*)(xb + (size_t)(i >> 5) * NC + (i & 31) * 8) = z;
    if (py == 55)
        for (int i = t; i < 1856; i += 256)
            *(u16x8*)(xb + (size_t)(57 * PW + (i >> 5)) * NC + (i & 31) * 8) = z;

    const float* xs = x + (size_t)b * NC * NPIX + py * HWD;
    int q = l & 15;
    int rb4 = l >> 4;
    #pragma unroll
    for (int it = 0; it < 16; ++it) {
        int c = wv * 64 + it * 4 + rb4;
        float4 v = {0.f, 0.f, 0.f, 0.f};
        if (q < 14) {
            v = *(const float4*)(xs + (size_t)c * NPIX + q * 4);
            unsigned short* tr = tile + c * TSTR + q * 4;
            tr[0] = f2bf(v.x); tr[1] = f2bf(v.y); tr[2] = f2bf(v.z); tr[3] = f2bf(v.w);
        }
        // fused GAP: reduce row-sum across the 16 q-lanes
        float s4 = v.x + v.y + v.z + v.w;
        s4 += __shfl_xor(s4, 1);
        s4 += __shfl_xor(s4, 2);
        s4 += __shfl_xor(s4, 4);
        s4 += __shfl_xor(s4, 8);
        if (q == 0) atomicAdd(&gap[b * NC + c], s4 * (1.0f / NPIX));
    }
    __syncthreads();
    int cch = t & 31, pg = t >> 5;
    for (int i = 0; i < 7; ++i) {
        int px = pg * 7 + i;
        u16x8 v;
        #pragma unroll
        for (int j = 0; j < 8; ++j) v[j] = tile[(cch * 8 + j) * TSTR + px];
        *(u16x8*)(xb + ((size_t)(1 + py) * PW + 1 + px) * NC + cch * 8) = v;
    }
}

// ---------------- main GEMM: R10 VERBATIM (proven 118.6 us, MfmaUtil 43.7%) ----------------
// 256oc x 224px tile, 8 waves (4M x 2N, wave 64x112). 3136 = 14*224 -> no pixel guards.
// K = 2304 = 72 steps of BK=32. Slice = 32KB, ring-4 = 128KB.
// issue(p+2) -> vmcnt(8)+barrier -> compute(p). R2-proven unit swizzle (0 conflicts).
#define SLICE 32768
#define BOFS  16384

#define PWAIT(N) do { asm volatile("s_waitcnt vmcnt(" #N ")" ::: "memory"); \
    __builtin_amdgcn_s_barrier(); __builtin_amdgcn_sched_barrier(0); } while (0)

__global__ __launch_bounds__(512, 2) void conv_gemm(
    const unsigned short* __restrict__ wa,   // [32][256][2304] bf16
    const unsigned short* __restrict__ xbt,  // [32][3364][256] bf16 (padded NHWC)
    float* __restrict__ out)                 // [32][256][3136]
{
    __shared__ __attribute__((aligned(16))) char lds[4 * SLICE];  // 128 KB

    // XCD swizzle: 448 blocks = 8 XCD * 56; 4 whole batches per XCD
    const int bid = blockIdx.x;
    const int wg  = (bid & 7) * 56 + (bid >> 3);
    const int b   = wg / 14, nt = wg % 14;

    const int t = threadIdx.x;
    const int w = t >> 6, l = t & 63;            // 8 waves
    const int wm = w >> 1, wn = w & 1;           // 4M x 2N, wave tile 64oc x 112px

    const unsigned short* waB = wa + (size_t)b * NOC * KTOT;
    const unsigned short* xbB = xbt + (size_t)b * PPIX * NC;

    // ---- staging sources (pre-swizzled, R2 mapping): chunk c = j*512 + t ----
    const unsigned short* srcA[2];
    const unsigned short* srcB[2];
    #pragma unroll
    for (int j = 0; j < 2; ++j) {
        int cix = j * 512 + t;
        int cc  = cix & 63;
        int row = (cix >> 6) * 16 + (cc >> 2);
        int qv  = (cc & 3) ^ ((cc >> 3) & 3);
        srcA[j] = waB + (size_t)row * KTOT + qv * 8;
        int pg = nt * 224 + row; if (pg > NPIX - 1) pg = NPIX - 1;  // pad units only
        int py = pg / 56, px = pg - py * 56;
        srcB[j] = xbB + (size_t)((py + 1) * PW + (px + 1)) * NC + qv * 8;
    }
    const int t16 = t * 16;

    auto issue = [&](int tp, int slot) {
        char* sb = lds + slot * SLICE;
        const int koff = tp * 32;                       // A: k = s*256+c linear
        const int s9 = tp >> 3;
        const int dy = (s9 >= 6) ? 2 : ((s9 >= 3) ? 1 : 0);
        const int dx = s9 - dy * 3;
        const int bsh = ((dy - 1) * PW + (dx - 1)) * NC + (tp & 7) * 32;
        #pragma unroll
        for (int j = 0; j < 2; ++j)
            __builtin_amdgcn_global_load_lds(
                (const __attribute__((address_space(1))) void*)(srcA[j] + koff),
                (__attribute__((address_space(3))) void*)(sb + j * 8192 + t16), 16, 0, 0);
        #pragma unroll
        for (int j = 0; j < 2; ++j)
            __builtin_amdgcn_global_load_lds(
                (const __attribute__((address_space(1))) void*)(srcB[j] + bsh),
                (__attribute__((address_space(3))) void*)(sb + BOFS + j * 8192 + t16), 16, 0, 0);
    };

    // ---- read-side lane constants (R2-proven, 0 conflicts) ----
    const int physq16 = (((l >> 4) ^ ((l >> 1) & 3)) << 4);
    const int arow = (l & 15) << 6;

    f32x4 acc[4][7] = {};

    auto compute = [&](int slot) {
        const char* sb = lds + slot * SLICE;
        bf16x8 af[4], bfr[7];
        #pragma unroll
        for (int m = 0; m < 4; ++m)
            af[m] = *(const bf16x8*)(sb + (wm * 4 + m) * 1024 + arow + physq16);
        #pragma unroll
        for (int j = 0; j < 7; ++j)
            bfr[j] = *(const bf16x8*)(sb + BOFS + (wn * 7 + j) * 1024 + arow + physq16);
        __builtin_amdgcn_s_setprio(1);
        #pragma unroll
        for (int m = 0; m < 4; ++m)
            #pragma unroll
            for (int j = 0; j < 7; ++j)
                acc[m][j] = __builtin_amdgcn_mfma_f32_16x16x32_bf16(af[m], bfr[j], acc[m][j], 0, 0, 0);
        __builtin_amdgcn_s_setprio(0);
    };

    issue(0, 0); issue(1, 1);

    #pragma unroll 4
    for (int p = 0; p < 70; ++p) {
        issue(p + 2, (p + 2) & 3);
        PWAIT(8);
        compute(p & 3);
    }
    PWAIT(4); compute(70 & 3);
    PWAIT(0); compute(71 & 3);

    // epilogue: D lane map col = l&15 (pixel), row = (l>>4)*4 + r (oc)
    const int ocb = wm * 64 + ((l >> 4) << 2);
    const int pxb = nt * 224 + wn * 112 + (l & 15);
    #pragma unroll
    for (int i = 0; i < 4; ++i) {
        #pragma unroll
        for (int j = 0; j < 7; ++j) {
            float* o = out + ((size_t)(b * NOC + ocb + i * 16)) * NPIX + pxb + j * 16;
            o[0]        = acc[i][j][0];
            o[NPIX]     = acc[i][j][1];
            o[2 * NPIX] = acc[i][j][2];
            o[3 * NPIX] = acc[i][j][3];
        }
    }
}

extern "C" void kernel_launch(void* const* d_in, const int* in_sizes, int n_in,
                              void* d_out, int out_size, void* d_ws, size_t ws_size,
                              hipStream_t stream) {
    (void)in_sizes; (void)n_in; (void)out_size; (void)ws_size;
    const float* x   = (const float*)d_in[0];
    const float* rw  = (const float*)d_in[1];
    const float* rb  = (const float*)d_in[2];
    const float* f1w = (const float*)d_in[3];
    const float* f2w = (const float*)d_in[4];
    const float* f2b = (const float*)d_in[5];
    float* out = (float*)d_out;

    char* wsb = (char*)d_ws;
    unsigned short* xbt = (unsigned short*)wsb;
    unsigned short* wa  = (unsigned short*)(wsb + XBT_BYTES);
    float* gap = (float*)(wsb + XBT_BYTES + WA_BYTES);

    hipMemsetAsync(gap, 0, (size_t)NB * NC * 4, stream);
    xpose_kernel<<<dim3(56, 32), 256, 0, stream>>>(x, xbt, gap);
    wk_kernel<<<dim3(256), 256, 0, stream>>>(gap, rw, rb, f1w, f2w, f2b, wa);
    conv_gemm<<<dim3(448), 512, 0, stream>>>(wa, xbt, out);
}